// Round 5
// baseline (533.825 us; speedup 1.0000x reference)
//
#include <hip/hip_runtime.h>

// Problem constants (fixed by reference)
constexpr int NROWS = 2048;
constexpr int NCOLS = 32000;
constexpr int NC4   = NCOLS / 4;   // 8000 float4 per row
constexpr int NMID  = 99;
constexpr int BLOCK = 512;         // 8 waves: 4 reader + 4 writer
constexpr int HALF  = 256;         // threads per role
constexpr int RWAVES = HALF / 64;  // 4 reader waves
constexpr int MAXC  = 16;          // candidate cap per row (expected ~0.5/row)
constexpr int PIPE  = 8;           // reader load pipeline depth

// NC4 = 8000 = 3*(PIPE*HALF=2048) + 7*HALF + 64  -> fully peelable, no guards
constexpr int MAIN_CHUNKS = 3;
constexpr int TAIL1_BASE  = MAIN_CHUNKS * PIPE * HALF;   // 6144
constexpr int TAIL1_DEPTH = 7;                            // 6144..7935
constexpr int TAIL2_BASE  = TAIL1_BASE + TAIL1_DEPTH * HALF; // 7936
constexpr int TAIL2_N     = NC4 - TAIL2_BASE;             // 64

typedef float vfloat4 __attribute__((ext_vector_type(4)));

__device__ inline float waveSum(float v) {
    #pragma unroll
    for (int off = 32; off > 0; off >>= 1)
        v += __shfl_down(v, off, 64);
    return v;
}

// ONE kernel, NO workspace (the 1 GB harness poison fill is unconditional —
// measured this round — so all we control is our own kernel's 160 us).
//
// R4 profile: VGPR_Count=28 proved the guarded 8-deep load pipeline was NOT
// materialized (compiler sank loads next to uses, ~2-deep). Fix: tail-peel so
// every hot load is unconditional; 8 back-to-back global_load_dwordx4 per
// chunk. Writers byte-identical to R2 (single-variable A/B).
__global__ __launch_bounds__(BLOCK, 4) void calib_wavesplit(
    const float* __restrict__ logits,
    const float* __restrict__ log_temperature,
    const float* __restrict__ iso_x,
    const float* __restrict__ iso_y,
    float* __restrict__ out)
{
    __shared__ float s_red[RWAVES];
    __shared__ float s_S;
    __shared__ int   s_cnt;
    __shared__ int   s_col[MAXC];
    __shared__ float s_z[MAXC];

    const int tid = threadIdx.x;
    const int row = blockIdx.x;

    if (tid == 0) s_cnt = 0;   // ordered before use by barrier #1

    float c0 = -3.4e38f, c1 = -3.4e38f;
    int   j0 = 0, j1 = 0;

    if (tid < HALF) {
        // ---- READERS: pure load stream, no stores in flight ----
        float T = expf(log_temperature[0]);
        T = fminf(fmaxf(T, 0.1f), 10.0f);
        const float rT = 1.0f / T;
        const int lane = tid & 63;
        const int wave = tid >> 6;

        const float4* __restrict__ row4 =
            reinterpret_cast<const float4*>(logits) + (size_t)row * NC4;

        float s0 = 0.0f, s1 = 0.0f;

        // candidate processing for one float4 at flat index idx
        auto process = [&](const float4& v, int idx) {
            const float za = v.x * rT, zb = v.y * rT;
            const float zc = v.z * rT, zd = v.w * rT;
            s0 += __expf(za) + __expf(zb);
            s1 += __expf(zc) + __expf(zd);
            const float qmax = fmaxf(fmaxf(za, zb), fmaxf(zc, zd));
            if (qmax > c1) {                       // rare, usually skipped
                const float zs[4] = {za, zb, zc, zd};
                #pragma unroll
                for (int k = 0; k < 4; ++k) {
                    const float zz = zs[k];
                    if (zz > c1) {
                        const int jj = idx * 4 + k;
                        if (zz > c0) { c1 = c0; j1 = j0; c0 = zz; j0 = jj; }
                        else         { c1 = zz; j1 = jj; }
                    }
                }
            }
        };

        // main: 3 chunks x 8 unconditional float4 loads (8 KB/wave in flight)
        int base = tid;
        #pragma unroll 1
        for (int c = 0; c < MAIN_CHUNKS; ++c, base += PIPE * HALF) {
            float4 v[PIPE];
            #pragma unroll
            for (int u = 0; u < PIPE; ++u) v[u] = row4[base + u * HALF];
            #pragma unroll
            for (int u = 0; u < PIPE; ++u) process(v[u], base + u * HALF);
        }
        // tail1: 7 unconditional loads (6144 + tid + u*256 <= 7935)
        {
            float4 v[TAIL1_DEPTH];
            #pragma unroll
            for (int u = 0; u < TAIL1_DEPTH; ++u)
                v[u] = row4[TAIL1_BASE + tid + u * HALF];
            #pragma unroll
            for (int u = 0; u < TAIL1_DEPTH; ++u)
                process(v[u], TAIL1_BASE + tid + u * HALF);
        }
        // tail2: last 64 float4 (only tid < 64)
        if (tid < TAIL2_N) {
            float4 v = row4[TAIL2_BASE + tid];
            process(v, TAIL2_BASE + tid);
        }

        float wsum = waveSum(s0 + s1);
        if (lane == 0) s_red[wave] = wsum;
    } else {
        // ---- WRITERS: fire-and-forget nontemporal fill (unchanged) ----
        const float y0 = iso_y[0];
        const vfloat4 fill = {y0, y0, y0, y0};
        vfloat4* out4 = reinterpret_cast<vfloat4*>(out) + (size_t)row * NC4;
        for (int i = tid - HALF; i < NC4; i += HALF)
            __builtin_nontemporal_store(fill, &out4[i]);
    }

    __syncthreads();   // #1: fill stores ack'd (vmcnt 0); reader partials visible

    if (tid == 0) s_S = s_red[0] + s_red[1] + s_red[2] + s_red[3];
    __syncthreads();   // #2

    const float S     = s_S;
    const float mids0 = 0.5f * (iso_x[0] + iso_x[1]);
    const float zcut  = logf(mids0 * S) - 1e-4f;   // conservative candidate cut

    if (c0 >= zcut) {
        int p = atomicAdd(&s_cnt, 1);
        if (p < MAXC) { s_col[p] = j0; s_z[p] = c0; }
    }
    if (c1 >= zcut) {
        int p = atomicAdd(&s_cnt, 1);
        if (p < MAXC) { s_col[p] = j1; s_z[p] = c1; }
    }
    __syncthreads();   // #3

    const int cnt = min(s_cnt, MAXC);
    if (tid < cnt) {
        const int   col = s_col[tid];
        const float z   = s_z[tid];
        const float p   = expf(z) / S;            // precise exp + IEEE div
        int ii = 0;
        while (ii < NMID && 0.5f * (iso_x[ii] + iso_x[ii + 1]) < p) ++ii;
        out[(size_t)row * NCOLS + col] = iso_y[ii];
    }
}

extern "C" void kernel_launch(void* const* d_in, const int* in_sizes, int n_in,
                              void* d_out, int out_size, void* d_ws, size_t ws_size,
                              hipStream_t stream) {
    const float* logits = (const float*)d_in[0];
    const float* logT   = (const float*)d_in[1];
    const float* iso_x  = (const float*)d_in[2];
    const float* iso_y  = (const float*)d_in[3];
    float* out = (float*)d_out;
    (void)d_ws; (void)ws_size;   // unused: harness poison is unconditional anyway

    calib_wavesplit<<<NROWS, BLOCK, 0, stream>>>(logits, logT, iso_x, iso_y, out);
}

// Round 7
// 450.226 us; speedup vs baseline: 1.1857x; 1.1857x over previous
//
#include <hip/hip_runtime.h>

// Problem constants (fixed by reference)
constexpr int NROWS = 2048;
constexpr int NCOLS = 32000;
constexpr int NC4   = NCOLS / 4;   // 8000 float4 per row
constexpr int NMID  = 99;
constexpr int BLOCK = 512;         // 8 waves: 4 reader + 4 writer
constexpr int HALF  = 256;         // threads per role
constexpr int RWAVES = HALF / 64;  // 4 reader waves
constexpr int MAXC  = 16;          // candidate cap per row (expected ~0.5/row)
constexpr int PIPE  = 8;           // reader load pipeline depth

typedef float vfloat4 __attribute__((ext_vector_type(4)));

__device__ inline float waveSum(float v) {
    #pragma unroll
    for (int off = 32; off > 0; off >>= 1)
        v += __shfl_down(v, off, 64);
    return v;
}

// ONE kernel. Harness window carries a constant ~289 us (unconditional 1 GB
// poison fill + resets) — only kernel time is controllable.
//
// R5 lesson: unconditional loads do NOT make the compiler keep 8 results live
// (VGPR 24, loads sunk next to uses, 2-deep rolling pipeline). This round:
// R4 loop shape (the faster variant) + sched_barrier(0) between the load
// cluster and the process cluster — nothing may cross, so all PIPE loads
// issue before the first use. Single-variable A/B vs R4's 160 us.
__global__ __launch_bounds__(BLOCK, 4) void calib_wavesplit(
    const float* __restrict__ logits,
    const float* __restrict__ log_temperature,
    const float* __restrict__ iso_x,
    const float* __restrict__ iso_y,
    float* __restrict__ out)
{
    __shared__ float s_red[RWAVES];
    __shared__ float s_S;
    __shared__ int   s_cnt;
    __shared__ int   s_col[MAXC];
    __shared__ float s_z[MAXC];

    const int tid = threadIdx.x;
    const int row = blockIdx.x;

    if (tid == 0) s_cnt = 0;   // ordered before use by barrier #1

    float c0 = -3.4e38f, c1 = -3.4e38f;
    int   j0 = 0, j1 = 0;

    if (tid < HALF) {
        // ---- READERS: pure load stream, no stores in flight ----
        float T = expf(log_temperature[0]);
        T = fminf(fmaxf(T, 0.1f), 10.0f);
        const float rT = 1.0f / T;
        const int lane = tid & 63;
        const int wave = tid >> 6;

        const float4* __restrict__ row4 =
            reinterpret_cast<const float4*>(logits) + (size_t)row * NC4;

        float s0 = 0.0f, s1 = 0.0f;

        for (int base = tid; base < NC4; base += PIPE * HALF) {
            float4 v[PIPE];
            #pragma unroll
            for (int u = 0; u < PIPE; ++u) {
                const int idx = base + u * HALF;
                if (idx < NC4) v[u] = row4[idx];
            }
            // Forbid the scheduler from sinking loads past this point:
            // all PIPE global_load_dwordx4 issue before the first use.
            __builtin_amdgcn_sched_barrier(0);
            #pragma unroll
            for (int u = 0; u < PIPE; ++u) {
                const int idx = base + u * HALF;
                if (idx < NC4) {
                    const float za = v[u].x * rT, zb = v[u].y * rT;
                    const float zc = v[u].z * rT, zd = v[u].w * rT;
                    s0 += __expf(za) + __expf(zb);
                    s1 += __expf(zc) + __expf(zd);
                    const float qmax = fmaxf(fmaxf(za, zb), fmaxf(zc, zd));
                    if (qmax > c1) {                // rare, usually skipped
                        const float zs[4] = {za, zb, zc, zd};
                        #pragma unroll
                        for (int k = 0; k < 4; ++k) {
                            const float zz = zs[k];
                            if (zz > c1) {
                                const int jj = idx * 4 + k;
                                if (zz > c0) { c1 = c0; j1 = j0; c0 = zz; j0 = jj; }
                                else         { c1 = zz; j1 = jj; }
                            }
                        }
                    }
                }
            }
        }

        float wsum = waveSum(s0 + s1);
        if (lane == 0) s_red[wave] = wsum;
    } else {
        // ---- WRITERS: fire-and-forget nontemporal fill (unchanged) ----
        const float y0 = iso_y[0];
        const vfloat4 fill = {y0, y0, y0, y0};
        vfloat4* out4 = reinterpret_cast<vfloat4*>(out) + (size_t)row * NC4;
        for (int i = tid - HALF; i < NC4; i += HALF)
            __builtin_nontemporal_store(fill, &out4[i]);
    }

    __syncthreads();   // #1: fill stores ack'd (vmcnt 0); reader partials visible

    if (tid == 0) s_S = s_red[0] + s_red[1] + s_red[2] + s_red[3];
    __syncthreads();   // #2

    const float S     = s_S;
    const float mids0 = 0.5f * (iso_x[0] + iso_x[1]);
    const float zcut  = logf(mids0 * S) - 1e-4f;   // conservative candidate cut

    if (c0 >= zcut) {
        int p = atomicAdd(&s_cnt, 1);
        if (p < MAXC) { s_col[p] = j0; s_z[p] = c0; }
    }
    if (c1 >= zcut) {
        int p = atomicAdd(&s_cnt, 1);
        if (p < MAXC) { s_col[p] = j1; s_z[p] = c1; }
    }
    __syncthreads();   // #3

    const int cnt = min(s_cnt, MAXC);
    if (tid < cnt) {
        const int   col = s_col[tid];
        const float z   = s_z[tid];
        const float p   = expf(z) / S;            // precise exp + IEEE div
        int ii = 0;
        while (ii < NMID && 0.5f * (iso_x[ii] + iso_x[ii + 1]) < p) ++ii;
        out[(size_t)row * NCOLS + col] = iso_y[ii];
    }
}

extern "C" void kernel_launch(void* const* d_in, const int* in_sizes, int n_in,
                              void* d_out, int out_size, void* d_ws, size_t ws_size,
                              hipStream_t stream) {
    const float* logits = (const float*)d_in[0];
    const float* logT   = (const float*)d_in[1];
    const float* iso_x  = (const float*)d_in[2];
    const float* iso_y  = (const float*)d_in[3];
    float* out = (float*)d_out;
    (void)d_ws; (void)ws_size;

    calib_wavesplit<<<NROWS, BLOCK, 0, stream>>>(logits, logT, iso_x, iso_y, out);
}